// Round 21
// baseline (159.103 us; speedup 1.0000x reference)
//
#include <hip/hip_runtime.h>
#include <hip/hip_bf16.h>
#include <math.h>

#define TT 8192
#define DD 512
#define HH 1024
#define EE 16
#define NSLOT 18432   // 144 * 128 max padded slots
#define MAXTILES 144
#define BM 128
#define RETRYCAP 1024

typedef __attribute__((ext_vector_type(8))) short bf16x8;
typedef __attribute__((ext_vector_type(8))) unsigned short u16x8;
typedef __attribute__((ext_vector_type(4))) float f32x4;

__device__ __forceinline__ unsigned short f2bf(float f) {
  union { float f; unsigned u; } v; v.f = f;
  unsigned r = v.u + 0x7fffu + ((v.u >> 16) & 1u);
  return (unsigned short)(r >> 16);
}

__device__ __forceinline__ float bf2f(unsigned short u) {
  union { unsigned u; float f; } v; v.u = ((unsigned)u) << 16;
  return v.f;
}

__device__ __forceinline__ void gload16(const void* g, void* l) {
  __builtin_amdgcn_global_load_lds(
      (const __attribute__((address_space(1))) unsigned int*)g,
      (__attribute__((address_space(3))) unsigned int*)l, 16, 0, 0);
}

// Abramowitz-Stegun 7.1.26 erf approx (|err| <= 1.5e-7)
__device__ __forceinline__ float gelu_f(float v) {
  float s = fabsf(v) * 0.70710678118654752f;
  float t = 1.0f / (1.0f + 0.3275911f * s);
  float poly = t * (0.254829592f +
              t * (-0.284496736f +
              t * (1.421413741f +
              t * (-1.453152027f +
              t * 1.061405429f))));
  float erfa = 1.0f - poly * __expf(-s * s);
  float erfv = (v >= 0.f) ? erfa : -erfa;
  return 0.5f * v * (1.0f + erfv);
}

// expert/row0 from counts: tile mt -> (expert, row0, valid)
__device__ __forceinline__ int tile_decode(const int* __restrict__ counts,
                                           int mt, int* e_out, int* row0_out) {
  int off = 0, rem = mt;
#pragma unroll
  for (int q = 0; q < EE; q++) {
    int tl = (counts[q] + BM - 1) / BM;
    if (rem < tl) { *e_out = q; *row0_out = off + rem * BM; return 1; }
    rem -= tl;
    off += tl * BM;
  }
  return 0;
}

// ---------------- prep: GATE blocks first (bid<128), then transposes --------
struct GateSm { float wg[DD * EE]; int cnt[EE]; };
union __align__(16) PrepSm {
  unsigned short t[64][68];
  GateSm g;
};

__global__ __launch_bounds__(256) void prep_kernel(
    const float* __restrict__ W1, const float* __restrict__ W2,
    unsigned short* __restrict__ w1t, unsigned short* __restrict__ w2t,
    const float* __restrict__ x, const float* __restrict__ Wg,
    const float* __restrict__ bg, unsigned short* __restrict__ xb,
    int* __restrict__ gate_e, float* __restrict__ gate_w,
    int* __restrict__ counts, int* __restrict__ nretry,
    int* __restrict__ retry) {
  __shared__ PrepSm sm;
  int bid = blockIdx.x;
  int tid = threadIdx.x;
  if (bid < 128) {
    // ---- gate: 64 tokens/block, barrier-free MFMA; Wg from LDS ----
    float* wg_s = sm.g.wg;
    if (tid < EE) sm.g.cnt[tid] = 0;
#pragma unroll
    for (int p = 0; p < 8; p++)
      ((float4*)wg_s)[p * 256 + tid] = ((const float4*)Wg)[p * 256 + tid];
    __syncthreads();
    int lane = tid & 63;
    int wave = tid >> 6;
    int tok0 = bid * 64 + wave * 16;
    int e = lane & 15;
    int kb = (lane >> 4) * 8;
    bf16x8 bfrag[16];
#pragma unroll
    for (int ks = 0; ks < 16; ks++) {
      int kbase = ks * 32 + kb;
#pragma unroll
      for (int j = 0; j < 8; j++)
        bfrag[ks][j] = (short)f2bf(wg_s[(kbase + j) * EE + e]);
    }
    float bge = bg[e];
    f32x4 acc = {0.f, 0.f, 0.f, 0.f};
    const float* xrow = x + (size_t)(tok0 + (lane & 15)) * DD + kb;
    unsigned short* xbrow = xb + (size_t)(tok0 + (lane & 15)) * DD + kb;
#pragma unroll 4
    for (int ks = 0; ks < 16; ks++) {
      int k0 = ks * 32;
      float4 v0 = *(const float4*)(xrow + k0);
      float4 v1 = *(const float4*)(xrow + k0 + 4);
      u16x8 w0;
      w0[0] = f2bf(v0.x); w0[1] = f2bf(v0.y); w0[2] = f2bf(v0.z); w0[3] = f2bf(v0.w);
      w0[4] = f2bf(v1.x); w0[5] = f2bf(v1.y); w0[6] = f2bf(v1.z); w0[7] = f2bf(v1.w);
      *(u16x8*)(xbrow + k0) = w0;
      union { u16x8 u; bf16x8 b; } cv; cv.u = w0;
      acc = __builtin_amdgcn_mfma_f32_16x16x32_bf16(cv.b, bfrag[ks], acc, 0, 0, 0);
    }
#pragma unroll
    for (int r = 0; r < 4; r++) {
      float lf = acc[r] + bge;
      float v1 = -1e30f, v2 = -1e30f, v3 = -1e30f;
      int i1 = 0, i2 = 0;
#pragma unroll
      for (int q = 0; q < EE; q++) {
        float v = __shfl(lf, (lane & 48) | q);
        if (v > v1) { v3 = v2; v2 = v1; i2 = i1; v1 = v; i1 = q; }
        else if (v > v2) { v3 = v2; v2 = v; i2 = q; }
        else if (v > v3) { v3 = v; }
      }
      if ((lane & 15) == 0) {
        int t2 = tok0 + ((lane >> 4) << 2) + r;
        float p = expf(v2 - v1);
        float s = 1.0f / (1.0f + p);
        gate_e[t2 * 2] = i1;
        gate_e[t2 * 2 + 1] = i2;
        gate_w[t2 * 2] = s;
        gate_w[t2 * 2 + 1] = p * s;
        atomicAdd(&sm.g.cnt[i1], 1);
        atomicAdd(&sm.g.cnt[i2], 1);
        if (v2 - v3 < 0.02f) {
          int pos = atomicAdd(nretry, 1);
          if (pos < RETRYCAP) retry[pos] = t2;
        }
      }
    }
    __syncthreads();
    if (tid < EE) atomicAdd(&counts[tid], sm.g.cnt[tid]);
    return;
  }
  // ---- transposes ----
  const float* src;
  unsigned short* dst;
  int R, C, c0, r0;
  int b = bid - 128;
  if (b < 2048) {
    int cx = b & 15, ry = (b >> 4) & 7, mat = b >> 7;
    src = W1 + (size_t)mat * DD * HH; dst = w1t + (size_t)mat * DD * HH;
    R = DD; C = HH; c0 = cx * 64; r0 = ry * 64;
  } else {
    b -= 2048;
    int cx = b & 7, ry = (b >> 3) & 15, mat = b >> 7;
    src = W2 + (size_t)mat * DD * HH; dst = w2t + (size_t)mat * DD * HH;
    R = HH; C = DD; c0 = cx * 64; r0 = ry * 64;
  }
#pragma unroll
  for (int p = 0; p < 4; p++) {
    int r = tid >> 2;
    int c4 = (tid & 3) + p * 4;
    float4 v = *(const float4*)(src + (size_t)(r0 + r) * C + c0 + c4 * 4);
    sm.t[c4 * 4 + 0][r] = f2bf(v.x);
    sm.t[c4 * 4 + 1][r] = f2bf(v.y);
    sm.t[c4 * 4 + 2][r] = f2bf(v.z);
    sm.t[c4 * 4 + 3][r] = f2bf(v.w);
  }
  __syncthreads();
#pragma unroll
  for (int p = 0; p < 4; p++) {
    int oc = (tid >> 4) + p * 16;
    int ch = tid & 15;
    ushort4 v = *(ushort4*)(&sm.t[oc][ch * 4]);
    *(ushort4*)(dst + (size_t)(c0 + oc) * R + r0 + ch * 4) = v;
  }
}

// ---------------- gatefix: exact f64 recompute for near-tie tokens ----------
__global__ __launch_bounds__(256) void gatefix_kernel(
    const float* __restrict__ x, const float* __restrict__ Wg,
    const float* __restrict__ bg, const int* __restrict__ nretry,
    const int* __restrict__ retry, int* __restrict__ gate_e,
    float* __restrict__ gate_w, int* __restrict__ counts) {
  __shared__ float lg[16][17];
  __shared__ int toks[16];
  int tid = threadIdx.x;
  int sl = tid >> 4, e = tid & 15;
  int s = blockIdx.x * 16 + sl;
  int n = *nretry; if (n > RETRYCAP) n = RETRYCAP;
  int active = (s < n);
  int tok = 0;
  if (active) tok = retry[s];
  if (active) {
    const float* xr = x + (size_t)tok * DD;
    double a0 = 0.0, a1 = 0.0, a2 = 0.0, a3 = 0.0;
    for (int i = 0; i < DD / 4; i++) {
      a0 += (double)xr[i * 4 + 0] * (double)Wg[(i * 4 + 0) * EE + e];
      a1 += (double)xr[i * 4 + 1] * (double)Wg[(i * 4 + 1) * EE + e];
      a2 += (double)xr[i * 4 + 2] * (double)Wg[(i * 4 + 2) * EE + e];
      a3 += (double)xr[i * 4 + 3] * (double)Wg[(i * 4 + 3) * EE + e];
    }
    double acc = (a0 + a1) + (a2 + a3);
    lg[sl][e] = (float)(acc + (double)bg[e]);
    toks[sl] = tok;
  }
  __syncthreads();
  if (active && e == 0) {
    float v1 = -1e30f, v2 = -1e30f;
    int i1 = 0, i2 = 0;
#pragma unroll
    for (int q = 0; q < EE; q++) {
      float v = lg[sl][q];
      if (v > v1) { v2 = v1; i2 = i1; v1 = v; i1 = q; }
      else if (v > v2) { v2 = v; i2 = q; }
    }
    int t2 = toks[sl];
    int o1 = gate_e[t2 * 2], o2 = gate_e[t2 * 2 + 1];
    float p = expf(v2 - v1);
    float sc = 1.0f / (1.0f + p);
    gate_e[t2 * 2] = i1;
    gate_e[t2 * 2 + 1] = i2;
    gate_w[t2 * 2] = sc;
    gate_w[t2 * 2 + 1] = p * sc;
    if (o1 != i1 || o2 != i2) {
      atomicSub(&counts[o1], 1);
      atomicSub(&counts[o2], 1);
      atomicAdd(&counts[i1], 1);
      atomicAdd(&counts[i2], 1);
    }
  }
}

// ---------------- scatter: hierarchical; block 0 also writes pad slots ------
__global__ __launch_bounds__(256) void scatter_kernel(
    const int* __restrict__ gate_e, const float* __restrict__ gate_w,
    const int* __restrict__ counts, int* __restrict__ fill,
    int* __restrict__ slot_token, float* __restrict__ slot_w,
    int* __restrict__ slot_of) {
  __shared__ int lcnt[EE];
  __shared__ int lbase[EE];
  __shared__ int offs_s[EE];
  int tid = threadIdx.x;
  int t = blockIdx.x * 256 + tid;
  if (tid < EE) lcnt[tid] = 0;
  if (tid == 0) {
    int off = 0;
    for (int q = 0; q < EE; q++) {
      offs_s[q] = off;
      off += ((counts[q] + BM - 1) / BM) * BM;
    }
  }
  __syncthreads();
  if (blockIdx.x == 0) {
#pragma unroll
    for (int q = 0; q < EE; q++) {
      int cnt = counts[q];
      int lim = ((cnt + BM - 1) / BM) * BM;
      for (int p = cnt + tid; p < lim; p += 256)
        slot_token[offs_s[q] + p] = -1;
    }
  }
  int e0 = gate_e[t * 2], e1 = gate_e[t * 2 + 1];
  int p0 = atomicAdd(&lcnt[e0], 1);
  int p1 = atomicAdd(&lcnt[e1], 1);
  __syncthreads();
  if (tid < EE) lbase[tid] = atomicAdd(&fill[tid], lcnt[tid]);
  __syncthreads();
  int s0 = offs_s[e0] + lbase[e0] + p0;
  int s1 = offs_s[e1] + lbase[e1] + p1;
  slot_token[s0] = t;
  slot_w[s0] = gate_w[t * 2];
  slot_of[t * 2] = s0;
  slot_token[s1] = t;
  slot_w[s1] = gate_w[t * 2 + 1];
  slot_of[t * 2 + 1] = s1;
}

// ---------------- GEMM1: 128x256 tile, BK=32, dbuf + counted-vmcnt ----------
// grid (MAXTILES, HH/256): tile = blockIdx.x -> wgid = tile + 144*n0b,
// 144%8==0 -> all n0-blocks of a tile land on XCD tile%8 -> the gathered
// A-panel becomes a same-XCD L2 hit for 3 of 4 readers (latency lever).
__global__ __launch_bounds__(512) void gemm1_kernel(
    const unsigned short* __restrict__ xb, const unsigned short* __restrict__ w1t,
    const float* __restrict__ b1, const int* __restrict__ slot_token,
    const int* __restrict__ counts, unsigned short* __restrict__ hb) {
  int e, row0;
  if (!tile_decode(counts, blockIdx.x, &e, &row0)) return;
  int n0 = blockIdx.y * 256;
  __shared__ unsigned short As[2][128][32];  // 16 KB
  __shared__ unsigned short Bs[2][256][32];  // 32 KB
  int tid = threadIdx.x;
  int lane = tid & 63;
  int wave = tid >> 6;
  int wm = wave >> 2, wn = wave & 3;
  int ra = tid >> 2, c = tid & 3;       // staging: row 0..127, chunk 0..3 (tid*16-linear)
  int tok_a = slot_token[row0 + ra]; if (tok_a < 0) tok_a = 0;
  const unsigned short* wbase = w1t + ((size_t)e * HH * DD);
  const unsigned short* gA  = xb + (size_t)tok_a * DD + c * 8;
  const unsigned short* gB0 = wbase + (size_t)(n0 + ra) * DD + c * 8;
  const unsigned short* gB1 = wbase + (size_t)(n0 + ra + 128) * DD + c * 8;
  f32x4 acc[4][4];
#pragma unroll
  for (int m = 0; m < 4; m++)
#pragma unroll
    for (int n = 0; n < 4; n++) {
      f32x4 z = {0.f, 0.f, 0.f, 0.f};
      acc[m][n] = z;
    }
  const int NK = DD / 32;
  gload16(gA, &As[0][ra][c * 8]);
  gload16(gB0, &Bs[0][ra][c * 8]);
  gload16(gB1, &Bs[0][ra + 128][c * 8]);
  for (int kk = 0; kk < NK; kk++) {
    int cur = kk & 1;
    if (kk + 1 < NK) {
      int k1 = (kk + 1) * 32;
      int nx = cur ^ 1;
      gload16(gA + k1, &As[nx][ra][c * 8]);
      gload16(gB0 + k1, &Bs[nx][ra][c * 8]);
      gload16(gB1 + k1, &Bs[nx][ra + 128][c * 8]);
      asm volatile("s_waitcnt vmcnt(3)" ::: "memory");
    } else {
      asm volatile("s_waitcnt vmcnt(0)" ::: "memory");
    }
    __builtin_amdgcn_s_barrier();
    bf16x8 a[4], b[4];
#pragma unroll
    for (int m = 0; m < 4; m++)
      a[m] = *(const bf16x8*)(&As[cur][wm * 64 + m * 16 + (lane & 15)][(lane >> 4) * 8]);
#pragma unroll
    for (int n = 0; n < 4; n++)
      b[n] = *(const bf16x8*)(&Bs[cur][wn * 64 + n * 16 + (lane & 15)][(lane >> 4) * 8]);
#pragma unroll
    for (int m = 0; m < 4; m++)
#pragma unroll
      for (int n = 0; n < 4; n++)
        acc[m][n] = __builtin_amdgcn_mfma_f32_16x16x32_bf16(a[m], b[n], acc[m][n], 0, 0, 0);
    asm volatile("" ::: "memory");
    __builtin_amdgcn_s_barrier();
  }
  const float* b1e = b1 + (size_t)e * HH;
#pragma unroll
  for (int m = 0; m < 4; m++) {
#pragma unroll
    for (int r = 0; r < 4; r++) {
      int slot = row0 + wm * 64 + m * 16 + ((lane >> 4) << 2) + r;
      unsigned short* hrow = hb + (size_t)slot * HH;
#pragma unroll
      for (int n = 0; n < 4; n++) {
        int hc = n0 + wn * 64 + n * 16 + (lane & 15);
        float v = acc[m][n][r] + b1e[hc];
        hrow[hc] = f2bf(gelu_f(v));
      }
    }
  }
}

// ---------------- GEMM2: 128x256 tile, BK=32, dbuf + counted-vmcnt ----------
// grid (MAXTILES, DD/256): same XCD co-location of A(hb)-panel sharers.
template <int USE_Y>
__global__ __launch_bounds__(512) void gemm2_kernel(
    const unsigned short* __restrict__ hb, const unsigned short* __restrict__ w2t,
    const float* __restrict__ b2, const int* __restrict__ slot_token,
    const float* __restrict__ slot_w, const int* __restrict__ counts,
    unsigned short* __restrict__ yw, float* __restrict__ out) {
  int e, row0;
  if (!tile_decode(counts, blockIdx.x, &e, &row0)) return;
  int n0 = blockIdx.y * 256;
  __shared__ unsigned short As[2][128][32];
  __shared__ unsigned short Bs[2][256][32];
  int tid = threadIdx.x;
  int lane = tid & 63;
  int wave = tid >> 6;
  int wm = wave >> 2, wn = wave & 3;
  int ra = tid >> 2, c = tid & 3;
  const unsigned short* wbase = w2t + ((size_t)e * DD * HH);
  const unsigned short* gA  = hb + (size_t)(row0 + ra) * HH + c * 8;
  const unsigned short* gB0 = wbase + (size_t)(n0 + ra) * HH + c * 8;
  const unsigned short* gB1 = wbase + (size_t)(n0 + ra + 128) * HH + c * 8;
  f32x4 acc[4][4];
#pragma unroll
  for (int m = 0; m < 4; m++)
#pragma unroll
    for (int n = 0; n < 4; n++) {
      f32x4 z = {0.f, 0.f, 0.f, 0.f};
      acc[m][n] = z;
    }
  const int NK = HH / 32;
  gload16(gA, &As[0][ra][c * 8]);
  gload16(gB0, &Bs[0][ra][c * 8]);
  gload16(gB1, &Bs[0][ra + 128][c * 8]);
  for (int kk = 0; kk < NK; kk++) {
    int cur = kk & 1;
    if (kk + 1 < NK) {
      int k1 = (kk + 1) * 32;
      int nx = cur ^ 1;
      gload16(gA + k1, &As[nx][ra][c * 8]);
      gload16(gB0 + k1, &Bs[nx][ra][c * 8]);
      gload16(gB1 + k1, &Bs[nx][ra + 128][c * 8]);
      asm volatile("s_waitcnt vmcnt(3)" ::: "memory");
    } else {
      asm volatile("s_waitcnt vmcnt(0)" ::: "memory");
    }
    __builtin_amdgcn_s_barrier();
    bf16x8 a[4], b[4];
#pragma unroll
    for (int m = 0; m < 4; m++)
      a[m] = *(const bf16x8*)(&As[cur][wm * 64 + m * 16 + (lane & 15)][(lane >> 4) * 8]);
#pragma unroll
    for (int n = 0; n < 4; n++)
      b[n] = *(const bf16x8*)(&Bs[cur][wn * 64 + n * 16 + (lane & 15)][(lane >> 4) * 8]);
#pragma unroll
    for (int m = 0; m < 4; m++)
#pragma unroll
      for (int n = 0; n < 4; n++)
        acc[m][n] = __builtin_amdgcn_mfma_f32_16x16x32_bf16(a[m], b[n], acc[m][n], 0, 0, 0);
    asm volatile("" ::: "memory");
    __builtin_amdgcn_s_barrier();
  }
  const float* b2e = b2 + (size_t)e * DD;
#pragma unroll
  for (int m = 0; m < 4; m++) {
#pragma unroll
    for (int r = 0; r < 4; r++) {
      int slot = row0 + wm * 64 + m * 16 + ((lane >> 4) << 2) + r;
      if (USE_Y) {
        float w = slot_w[slot];
        unsigned short* yrow = yw + (size_t)slot * DD;
#pragma unroll
        for (int n = 0; n < 4; n++) {
          int dc = n0 + wn * 64 + n * 16 + (lane & 15);
          yrow[dc] = f2bf(w * (acc[m][n][r] + b2e[dc]));
        }
      } else {
        int tok = slot_token[slot];
        if (tok >= 0) {
          float w = slot_w[slot];
          float* orow = out + (size_t)tok * DD;
#pragma unroll
          for (int n = 0; n < 4; n++) {
            int dc = n0 + wn * 64 + n * 16 + (lane & 15);
            float v = acc[m][n][r] + b2e[dc];
            atomicAdd(&orow[dc], w * v);
          }
        }
      }
    }
  }
}

// ---------------- combine: out[t] = yw[s1] + yw[s2] ----------------
__global__ __launch_bounds__(256) void combine_kernel(
    const unsigned short* __restrict__ yw, const int* __restrict__ slot_of,
    float* __restrict__ out) {
  int gid = blockIdx.x * 256 + threadIdx.x;
  int t = gid >> 6;
  int d0 = (gid & 63) * 8;
  int s1 = slot_of[t * 2], s2 = slot_of[t * 2 + 1];
  const ushort4* p1 = (const ushort4*)(yw + (size_t)s1 * DD + d0);
  const ushort4* p2 = (const ushort4*)(yw + (size_t)s2 * DD + d0);
  ushort4 a0 = p1[0], a1 = p1[1];
  ushort4 b0 = p2[0], b1 = p2[1];
  float4 o0, o1;
  o0.x = bf2f(a0.x) + bf2f(b0.x);
  o0.y = bf2f(a0.y) + bf2f(b0.y);
  o0.z = bf2f(a0.z) + bf2f(b0.z);
  o0.w = bf2f(a0.w) + bf2f(b0.w);
  o1.x = bf2f(a1.x) + bf2f(b1.x);
  o1.y = bf2f(a1.y) + bf2f(b1.y);
  o1.z = bf2f(a1.z) + bf2f(b1.z);
  o1.w = bf2f(a1.w) + bf2f(b1.w);
  float* orow = out + (size_t)t * DD + d0;
  ((float4*)orow)[0] = o0;
  ((float4*)orow)[1] = o1;
}

extern "C" void kernel_launch(void* const* d_in, const int* in_sizes, int n_in,
                              void* d_out, int out_size, void* d_ws, size_t ws_size,
                              hipStream_t stream) {
  const float* x  = (const float*)d_in[0];
  const float* Wg = (const float*)d_in[1];
  const float* bg = (const float*)d_in[2];
  const float* W1 = (const float*)d_in[3];
  const float* b1 = (const float*)d_in[4];
  const float* W2 = (const float*)d_in[5];
  const float* b2 = (const float*)d_in[6];
  float* out = (float*)d_out;

  uint8_t* w = (uint8_t*)d_ws;
  size_t o = 0;
  unsigned short* xb  = (unsigned short*)(w + o); o += (size_t)TT * DD * 2;       // 8 MB
  unsigned short* w1t = (unsigned short*)(w + o); o += (size_t)EE * DD * HH * 2;  // 16 MB
  unsigned short* w2t = (unsigned short*)(w + o); o += (size_t)EE * DD * HH * 2;  // 16 MB
  unsigned short* hb  = (unsigned short*)(w + o); o += (size_t)NSLOT * HH * 2;    // 37.7 MB
  int*   slot_token = (int*)(w + o);   o += (size_t)NSLOT * 4;
  float* slot_w     = (float*)(w + o); o += (size_t)NSLOT * 4;
  int*   slot_of    = (int*)(w + o);   o += (size_t)TT * 2 * 4;
  int*   gate_e     = (int*)(w + o);   o += (size_t)TT * 2 * 4;
  float* gate_w     = (float*)(w + o); o += (size_t)TT * 2 * 4;
  int*   counts     = (int*)(w + o);   o += 64;   // counts[16]
  int*   nretry     = (int*)(w + o);   o += 64;
  int*   fill       = (int*)(w + o);   o += 64;   // one 192B memset covers all 3
  int*   retry      = (int*)(w + o);   o += RETRYCAP * 4;
  unsigned short* yw = (unsigned short*)(w + o);
  size_t need_y = o + (size_t)NSLOT * DD * 2;   // +18.9 MB
  int use_y = (ws_size >= need_y);

  hipMemsetAsync(counts, 0, 192, stream);  // counts + nretry + fill
  if (!use_y) {
    hipMemsetAsync(slot_token, 0xFF, (size_t)NSLOT * 4, stream);
    hipMemsetAsync(d_out, 0, (size_t)TT * DD * 4, stream);
  }

  // gate (blocks 0..127, dispatched first) + W1/W2 transposes (128..4223)
  prep_kernel<<<128 + 4096, 256, 0, stream>>>(
      W1, W2, w1t, w2t, x, Wg, bg, xb, gate_e, gate_w, counts, nretry, retry);
  gatefix_kernel<<<RETRYCAP / 16, 256, 0, stream>>>(x, Wg, bg, nretry, retry,
                                                    gate_e, gate_w, counts);
  scatter_kernel<<<TT / 256, 256, 0, stream>>>(gate_e, gate_w, counts, fill,
                                               slot_token, slot_w, slot_of);
  {
    dim3 g(MAXTILES, HH / 256);
    gemm1_kernel<<<g, 512, 0, stream>>>(xb, w1t, b1, slot_token, counts, hb);
  }
  {
    dim3 g(MAXTILES, DD / 256);
    if (use_y)
      gemm2_kernel<1><<<g, 512, 0, stream>>>(hb, w2t, b2, slot_token, slot_w,
                                             counts, yw, out);
    else
      gemm2_kernel<0><<<g, 512, 0, stream>>>(hb, w2t, b2, slot_token, slot_w,
                                             counts, yw, out);
  }
  if (use_y) {
    combine_kernel<<<TT * (DD / 8) / 256, 256, 0, stream>>>(yw, slot_of, out);
  }
}

// Round 22
// 154.884 us; speedup vs baseline: 1.0272x; 1.0272x over previous
//
#include <hip/hip_runtime.h>
#include <hip/hip_bf16.h>
#include <math.h>

#define TT 8192
#define DD 512
#define HH 1024
#define EE 16
#define NSLOT 18432   // 144 * 128 max padded slots
#define MAXTILES 144
#define BM 128
#define RETRYCAP 1024

typedef __attribute__((ext_vector_type(8))) short bf16x8;
typedef __attribute__((ext_vector_type(8))) unsigned short u16x8;
typedef __attribute__((ext_vector_type(4))) float f32x4;

__device__ __forceinline__ unsigned short f2bf(float f) {
  union { float f; unsigned u; } v; v.f = f;
  unsigned r = v.u + 0x7fffu + ((v.u >> 16) & 1u);
  return (unsigned short)(r >> 16);
}

__device__ __forceinline__ float bf2f(unsigned short u) {
  union { unsigned u; float f; } v; v.u = ((unsigned)u) << 16;
  return v.f;
}

__device__ __forceinline__ void gload16(const void* g, void* l) {
  __builtin_amdgcn_global_load_lds(
      (const __attribute__((address_space(1))) unsigned int*)g,
      (__attribute__((address_space(3))) unsigned int*)l, 16, 0, 0);
}

// Abramowitz-Stegun 7.1.26 erf approx (|err| <= 1.5e-7)
__device__ __forceinline__ float gelu_f(float v) {
  float s = fabsf(v) * 0.70710678118654752f;
  float t = 1.0f / (1.0f + 0.3275911f * s);
  float poly = t * (0.254829592f +
              t * (-0.284496736f +
              t * (1.421413741f +
              t * (-1.453152027f +
              t * 1.061405429f))));
  float erfa = 1.0f - poly * __expf(-s * s);
  float erfv = (v >= 0.f) ? erfa : -erfa;
  return 0.5f * v * (1.0f + erfv);
}

// expert/row0 from counts: tile mt -> (expert, row0, valid)
__device__ __forceinline__ int tile_decode(const int* __restrict__ counts,
                                           int mt, int* e_out, int* row0_out) {
  int off = 0, rem = mt;
#pragma unroll
  for (int q = 0; q < EE; q++) {
    int tl = (counts[q] + BM - 1) / BM;
    if (rem < tl) { *e_out = q; *row0_out = off + rem * BM; return 1; }
    rem -= tl;
    off += tl * BM;
  }
  return 0;
}

// ---------------- prep: GATE blocks first (bid<128), then transposes --------
struct GateSm { float wg[DD * EE]; int cnt[EE]; };
union __align__(16) PrepSm {
  unsigned short t[64][68];
  GateSm g;
};

__global__ __launch_bounds__(256) void prep_kernel(
    const float* __restrict__ W1, const float* __restrict__ W2,
    unsigned short* __restrict__ w1t, unsigned short* __restrict__ w2t,
    const float* __restrict__ x, const float* __restrict__ Wg,
    const float* __restrict__ bg, unsigned short* __restrict__ xb,
    int* __restrict__ gate_e, float* __restrict__ gate_w,
    int* __restrict__ counts, int* __restrict__ nretry,
    int* __restrict__ retry) {
  __shared__ PrepSm sm;
  int bid = blockIdx.x;
  int tid = threadIdx.x;
  if (bid < 128) {
    // ---- gate: 64 tokens/block, barrier-free MFMA; Wg from LDS ----
    float* wg_s = sm.g.wg;
    if (tid < EE) sm.g.cnt[tid] = 0;
#pragma unroll
    for (int p = 0; p < 8; p++)
      ((float4*)wg_s)[p * 256 + tid] = ((const float4*)Wg)[p * 256 + tid];
    __syncthreads();
    int lane = tid & 63;
    int wave = tid >> 6;
    int tok0 = bid * 64 + wave * 16;
    int e = lane & 15;
    int kb = (lane >> 4) * 8;
    bf16x8 bfrag[16];
#pragma unroll
    for (int ks = 0; ks < 16; ks++) {
      int kbase = ks * 32 + kb;
#pragma unroll
      for (int j = 0; j < 8; j++)
        bfrag[ks][j] = (short)f2bf(wg_s[(kbase + j) * EE + e]);
    }
    float bge = bg[e];
    f32x4 acc = {0.f, 0.f, 0.f, 0.f};
    const float* xrow = x + (size_t)(tok0 + (lane & 15)) * DD + kb;
    unsigned short* xbrow = xb + (size_t)(tok0 + (lane & 15)) * DD + kb;
#pragma unroll 4
    for (int ks = 0; ks < 16; ks++) {
      int k0 = ks * 32;
      float4 v0 = *(const float4*)(xrow + k0);
      float4 v1 = *(const float4*)(xrow + k0 + 4);
      u16x8 w0;
      w0[0] = f2bf(v0.x); w0[1] = f2bf(v0.y); w0[2] = f2bf(v0.z); w0[3] = f2bf(v0.w);
      w0[4] = f2bf(v1.x); w0[5] = f2bf(v1.y); w0[6] = f2bf(v1.z); w0[7] = f2bf(v1.w);
      *(u16x8*)(xbrow + k0) = w0;
      union { u16x8 u; bf16x8 b; } cv; cv.u = w0;
      acc = __builtin_amdgcn_mfma_f32_16x16x32_bf16(cv.b, bfrag[ks], acc, 0, 0, 0);
    }
#pragma unroll
    for (int r = 0; r < 4; r++) {
      float lf = acc[r] + bge;
      float v1 = -1e30f, v2 = -1e30f, v3 = -1e30f;
      int i1 = 0, i2 = 0;
#pragma unroll
      for (int q = 0; q < EE; q++) {
        float v = __shfl(lf, (lane & 48) | q);
        if (v > v1) { v3 = v2; v2 = v1; i2 = i1; v1 = v; i1 = q; }
        else if (v > v2) { v3 = v2; v2 = v; i2 = q; }
        else if (v > v3) { v3 = v; }
      }
      if ((lane & 15) == 0) {
        int t2 = tok0 + ((lane >> 4) << 2) + r;
        float p = expf(v2 - v1);
        float s = 1.0f / (1.0f + p);
        gate_e[t2 * 2] = i1;
        gate_e[t2 * 2 + 1] = i2;
        gate_w[t2 * 2] = s;
        gate_w[t2 * 2 + 1] = p * s;
        atomicAdd(&sm.g.cnt[i1], 1);
        atomicAdd(&sm.g.cnt[i2], 1);
        if (v2 - v3 < 0.02f) {
          int pos = atomicAdd(nretry, 1);
          if (pos < RETRYCAP) retry[pos] = t2;
        }
      }
    }
    __syncthreads();
    if (tid < EE) atomicAdd(&counts[tid], sm.g.cnt[tid]);
    return;
  }
  // ---- transposes ----
  const float* src;
  unsigned short* dst;
  int R, C, c0, r0;
  int b = bid - 128;
  if (b < 2048) {
    int cx = b & 15, ry = (b >> 4) & 7, mat = b >> 7;
    src = W1 + (size_t)mat * DD * HH; dst = w1t + (size_t)mat * DD * HH;
    R = DD; C = HH; c0 = cx * 64; r0 = ry * 64;
  } else {
    b -= 2048;
    int cx = b & 7, ry = (b >> 3) & 15, mat = b >> 7;
    src = W2 + (size_t)mat * DD * HH; dst = w2t + (size_t)mat * DD * HH;
    R = HH; C = DD; c0 = cx * 64; r0 = ry * 64;
  }
#pragma unroll
  for (int p = 0; p < 4; p++) {
    int r = tid >> 2;
    int c4 = (tid & 3) + p * 4;
    float4 v = *(const float4*)(src + (size_t)(r0 + r) * C + c0 + c4 * 4);
    sm.t[c4 * 4 + 0][r] = f2bf(v.x);
    sm.t[c4 * 4 + 1][r] = f2bf(v.y);
    sm.t[c4 * 4 + 2][r] = f2bf(v.z);
    sm.t[c4 * 4 + 3][r] = f2bf(v.w);
  }
  __syncthreads();
#pragma unroll
  for (int p = 0; p < 4; p++) {
    int oc = (tid >> 4) + p * 16;
    int ch = tid & 15;
    ushort4 v = *(ushort4*)(&sm.t[oc][ch * 4]);
    *(ushort4*)(dst + (size_t)(c0 + oc) * R + r0 + ch * 4) = v;
  }
}

// ---------------- gatefix: exact f64 recompute for near-tie tokens ----------
__global__ __launch_bounds__(256) void gatefix_kernel(
    const float* __restrict__ x, const float* __restrict__ Wg,
    const float* __restrict__ bg, const int* __restrict__ nretry,
    const int* __restrict__ retry, int* __restrict__ gate_e,
    float* __restrict__ gate_w, int* __restrict__ counts) {
  __shared__ float lg[16][17];
  __shared__ int toks[16];
  int tid = threadIdx.x;
  int sl = tid >> 4, e = tid & 15;
  int s = blockIdx.x * 16 + sl;
  int n = *nretry; if (n > RETRYCAP) n = RETRYCAP;
  int active = (s < n);
  int tok = 0;
  if (active) tok = retry[s];
  if (active) {
    const float* xr = x + (size_t)tok * DD;
    double a0 = 0.0, a1 = 0.0, a2 = 0.0, a3 = 0.0;
    for (int i = 0; i < DD / 4; i++) {
      a0 += (double)xr[i * 4 + 0] * (double)Wg[(i * 4 + 0) * EE + e];
      a1 += (double)xr[i * 4 + 1] * (double)Wg[(i * 4 + 1) * EE + e];
      a2 += (double)xr[i * 4 + 2] * (double)Wg[(i * 4 + 2) * EE + e];
      a3 += (double)xr[i * 4 + 3] * (double)Wg[(i * 4 + 3) * EE + e];
    }
    double acc = (a0 + a1) + (a2 + a3);
    lg[sl][e] = (float)(acc + (double)bg[e]);
    toks[sl] = tok;
  }
  __syncthreads();
  if (active && e == 0) {
    float v1 = -1e30f, v2 = -1e30f;
    int i1 = 0, i2 = 0;
#pragma unroll
    for (int q = 0; q < EE; q++) {
      float v = lg[sl][q];
      if (v > v1) { v2 = v1; i2 = i1; v1 = v; i1 = q; }
      else if (v > v2) { v2 = v; i2 = q; }
    }
    int t2 = toks[sl];
    int o1 = gate_e[t2 * 2], o2 = gate_e[t2 * 2 + 1];
    float p = expf(v2 - v1);
    float sc = 1.0f / (1.0f + p);
    gate_e[t2 * 2] = i1;
    gate_e[t2 * 2 + 1] = i2;
    gate_w[t2 * 2] = sc;
    gate_w[t2 * 2 + 1] = p * sc;
    if (o1 != i1 || o2 != i2) {
      atomicSub(&counts[o1], 1);
      atomicSub(&counts[o2], 1);
      atomicAdd(&counts[i1], 1);
      atomicAdd(&counts[i2], 1);
    }
  }
}

// ---------------- scatter: hierarchical; block 0 also writes pad slots ------
__global__ __launch_bounds__(256) void scatter_kernel(
    const int* __restrict__ gate_e, const float* __restrict__ gate_w,
    const int* __restrict__ counts, int* __restrict__ fill,
    int* __restrict__ slot_token, float* __restrict__ slot_w,
    int* __restrict__ slot_of) {
  __shared__ int lcnt[EE];
  __shared__ int lbase[EE];
  __shared__ int offs_s[EE];
  int tid = threadIdx.x;
  int t = blockIdx.x * 256 + tid;
  if (tid < EE) lcnt[tid] = 0;
  if (tid == 0) {
    int off = 0;
    for (int q = 0; q < EE; q++) {
      offs_s[q] = off;
      off += ((counts[q] + BM - 1) / BM) * BM;
    }
  }
  __syncthreads();
  if (blockIdx.x == 0) {
#pragma unroll
    for (int q = 0; q < EE; q++) {
      int cnt = counts[q];
      int lim = ((cnt + BM - 1) / BM) * BM;
      for (int p = cnt + tid; p < lim; p += 256)
        slot_token[offs_s[q] + p] = -1;
    }
  }
  int e0 = gate_e[t * 2], e1 = gate_e[t * 2 + 1];
  int p0 = atomicAdd(&lcnt[e0], 1);
  int p1 = atomicAdd(&lcnt[e1], 1);
  __syncthreads();
  if (tid < EE) lbase[tid] = atomicAdd(&fill[tid], lcnt[tid]);
  __syncthreads();
  int s0 = offs_s[e0] + lbase[e0] + p0;
  int s1 = offs_s[e1] + lbase[e1] + p1;
  slot_token[s0] = t;
  slot_w[s0] = gate_w[t * 2];
  slot_of[t * 2] = s0;
  slot_token[s1] = t;
  slot_w[s1] = gate_w[t * 2 + 1];
  slot_of[t * 2 + 1] = s1;
}

// ---------------- GEMM1: 128x256 tile, BK=32, dbuf + counted-vmcnt ----------
// grid (HH/256, MAXTILES): n0-major dispatch keeps B-panel sharers
// co-scheduled (R21 showed tile-major doubles FETCH).
__global__ __launch_bounds__(512) void gemm1_kernel(
    const unsigned short* __restrict__ xb, const unsigned short* __restrict__ w1t,
    const float* __restrict__ b1, const int* __restrict__ slot_token,
    const int* __restrict__ counts, unsigned short* __restrict__ hb) {
  int e, row0;
  if (!tile_decode(counts, blockIdx.y, &e, &row0)) return;
  int n0 = blockIdx.x * 256;
  __shared__ unsigned short As[2][128][32];  // 16 KB
  __shared__ unsigned short Bs[2][256][32];  // 32 KB
  int tid = threadIdx.x;
  int lane = tid & 63;
  int wave = tid >> 6;
  int wm = wave >> 2, wn = wave & 3;
  int ra = tid >> 2, c = tid & 3;       // staging: row 0..127, chunk 0..3 (tid*16-linear)
  int tok_a = slot_token[row0 + ra]; if (tok_a < 0) tok_a = 0;
  const unsigned short* wbase = w1t + ((size_t)e * HH * DD);
  const unsigned short* gA  = xb + (size_t)tok_a * DD + c * 8;
  const unsigned short* gB0 = wbase + (size_t)(n0 + ra) * DD + c * 8;
  const unsigned short* gB1 = wbase + (size_t)(n0 + ra + 128) * DD + c * 8;
  f32x4 acc[4][4];
#pragma unroll
  for (int m = 0; m < 4; m++)
#pragma unroll
    for (int n = 0; n < 4; n++) {
      f32x4 z = {0.f, 0.f, 0.f, 0.f};
      acc[m][n] = z;
    }
  const int NK = DD / 32;
  gload16(gA, &As[0][ra][c * 8]);
  gload16(gB0, &Bs[0][ra][c * 8]);
  gload16(gB1, &Bs[0][ra + 128][c * 8]);
  for (int kk = 0; kk < NK; kk++) {
    int cur = kk & 1;
    if (kk + 1 < NK) {
      int k1 = (kk + 1) * 32;
      int nx = cur ^ 1;
      gload16(gA + k1, &As[nx][ra][c * 8]);
      gload16(gB0 + k1, &Bs[nx][ra][c * 8]);
      gload16(gB1 + k1, &Bs[nx][ra + 128][c * 8]);
      asm volatile("s_waitcnt vmcnt(3)" ::: "memory");
    } else {
      asm volatile("s_waitcnt vmcnt(0)" ::: "memory");
    }
    __builtin_amdgcn_s_barrier();
    bf16x8 a[4], b[4];
#pragma unroll
    for (int m = 0; m < 4; m++)
      a[m] = *(const bf16x8*)(&As[cur][wm * 64 + m * 16 + (lane & 15)][(lane >> 4) * 8]);
#pragma unroll
    for (int n = 0; n < 4; n++)
      b[n] = *(const bf16x8*)(&Bs[cur][wn * 64 + n * 16 + (lane & 15)][(lane >> 4) * 8]);
#pragma unroll
    for (int m = 0; m < 4; m++)
#pragma unroll
      for (int n = 0; n < 4; n++)
        acc[m][n] = __builtin_amdgcn_mfma_f32_16x16x32_bf16(a[m], b[n], acc[m][n], 0, 0, 0);
    asm volatile("" ::: "memory");
    __builtin_amdgcn_s_barrier();
  }
  const float* b1e = b1 + (size_t)e * HH;
#pragma unroll
  for (int m = 0; m < 4; m++) {
#pragma unroll
    for (int r = 0; r < 4; r++) {
      int slot = row0 + wm * 64 + m * 16 + ((lane >> 4) << 2) + r;
      unsigned short* hrow = hb + (size_t)slot * HH;
#pragma unroll
      for (int n = 0; n < 4; n++) {
        int hc = n0 + wn * 64 + n * 16 + (lane & 15);
        float v = acc[m][n][r] + b1e[hc];
        hrow[hc] = f2bf(gelu_f(v));
      }
    }
  }
}

// ---------------- GEMM2: 128x256 tile, BK=32, dbuf + counted-vmcnt ----------
// grid (DD/256, MAXTILES)
template <int USE_Y>
__global__ __launch_bounds__(512) void gemm2_kernel(
    const unsigned short* __restrict__ hb, const unsigned short* __restrict__ w2t,
    const float* __restrict__ b2, const int* __restrict__ slot_token,
    const float* __restrict__ slot_w, const int* __restrict__ counts,
    unsigned short* __restrict__ yw, float* __restrict__ out) {
  int e, row0;
  if (!tile_decode(counts, blockIdx.y, &e, &row0)) return;
  int n0 = blockIdx.x * 256;
  __shared__ unsigned short As[2][128][32];
  __shared__ unsigned short Bs[2][256][32];
  int tid = threadIdx.x;
  int lane = tid & 63;
  int wave = tid >> 6;
  int wm = wave >> 2, wn = wave & 3;
  int ra = tid >> 2, c = tid & 3;
  const unsigned short* wbase = w2t + ((size_t)e * DD * HH);
  const unsigned short* gA  = hb + (size_t)(row0 + ra) * HH + c * 8;
  const unsigned short* gB0 = wbase + (size_t)(n0 + ra) * HH + c * 8;
  const unsigned short* gB1 = wbase + (size_t)(n0 + ra + 128) * HH + c * 8;
  f32x4 acc[4][4];
#pragma unroll
  for (int m = 0; m < 4; m++)
#pragma unroll
    for (int n = 0; n < 4; n++) {
      f32x4 z = {0.f, 0.f, 0.f, 0.f};
      acc[m][n] = z;
    }
  const int NK = HH / 32;
  gload16(gA, &As[0][ra][c * 8]);
  gload16(gB0, &Bs[0][ra][c * 8]);
  gload16(gB1, &Bs[0][ra + 128][c * 8]);
  for (int kk = 0; kk < NK; kk++) {
    int cur = kk & 1;
    if (kk + 1 < NK) {
      int k1 = (kk + 1) * 32;
      int nx = cur ^ 1;
      gload16(gA + k1, &As[nx][ra][c * 8]);
      gload16(gB0 + k1, &Bs[nx][ra][c * 8]);
      gload16(gB1 + k1, &Bs[nx][ra + 128][c * 8]);
      asm volatile("s_waitcnt vmcnt(3)" ::: "memory");
    } else {
      asm volatile("s_waitcnt vmcnt(0)" ::: "memory");
    }
    __builtin_amdgcn_s_barrier();
    bf16x8 a[4], b[4];
#pragma unroll
    for (int m = 0; m < 4; m++)
      a[m] = *(const bf16x8*)(&As[cur][wm * 64 + m * 16 + (lane & 15)][(lane >> 4) * 8]);
#pragma unroll
    for (int n = 0; n < 4; n++)
      b[n] = *(const bf16x8*)(&Bs[cur][wn * 64 + n * 16 + (lane & 15)][(lane >> 4) * 8]);
#pragma unroll
    for (int m = 0; m < 4; m++)
#pragma unroll
      for (int n = 0; n < 4; n++)
        acc[m][n] = __builtin_amdgcn_mfma_f32_16x16x32_bf16(a[m], b[n], acc[m][n], 0, 0, 0);
    asm volatile("" ::: "memory");
    __builtin_amdgcn_s_barrier();
  }
  const float* b2e = b2 + (size_t)e * DD;
#pragma unroll
  for (int m = 0; m < 4; m++) {
#pragma unroll
    for (int r = 0; r < 4; r++) {
      int slot = row0 + wm * 64 + m * 16 + ((lane >> 4) << 2) + r;
      if (USE_Y) {
        float w = slot_w[slot];
        unsigned short* yrow = yw + (size_t)slot * DD;
#pragma unroll
        for (int n = 0; n < 4; n++) {
          int dc = n0 + wn * 64 + n * 16 + (lane & 15);
          yrow[dc] = f2bf(w * (acc[m][n][r] + b2e[dc]));
        }
      } else {
        int tok = slot_token[slot];
        if (tok >= 0) {
          float w = slot_w[slot];
          float* orow = out + (size_t)tok * DD;
#pragma unroll
          for (int n = 0; n < 4; n++) {
            int dc = n0 + wn * 64 + n * 16 + (lane & 15);
            float v = acc[m][n][r] + b2e[dc];
            atomicAdd(&orow[dc], w * v);
          }
        }
      }
    }
  }
}

// ---------------- combine: out[t] = yw[s1] + yw[s2] ----------------
__global__ __launch_bounds__(256) void combine_kernel(
    const unsigned short* __restrict__ yw, const int* __restrict__ slot_of,
    float* __restrict__ out) {
  int gid = blockIdx.x * 256 + threadIdx.x;
  int t = gid >> 6;
  int d0 = (gid & 63) * 8;
  int s1 = slot_of[t * 2], s2 = slot_of[t * 2 + 1];
  const ushort4* p1 = (const ushort4*)(yw + (size_t)s1 * DD + d0);
  const ushort4* p2 = (const ushort4*)(yw + (size_t)s2 * DD + d0);
  ushort4 a0 = p1[0], a1 = p1[1];
  ushort4 b0 = p2[0], b1 = p2[1];
  float4 o0, o1;
  o0.x = bf2f(a0.x) + bf2f(b0.x);
  o0.y = bf2f(a0.y) + bf2f(b0.y);
  o0.z = bf2f(a0.z) + bf2f(b0.z);
  o0.w = bf2f(a0.w) + bf2f(b0.w);
  o1.x = bf2f(a1.x) + bf2f(b1.x);
  o1.y = bf2f(a1.y) + bf2f(b1.y);
  o1.z = bf2f(a1.z) + bf2f(b1.z);
  o1.w = bf2f(a1.w) + bf2f(b1.w);
  float* orow = out + (size_t)t * DD + d0;
  ((float4*)orow)[0] = o0;
  ((float4*)orow)[1] = o1;
}

extern "C" void kernel_launch(void* const* d_in, const int* in_sizes, int n_in,
                              void* d_out, int out_size, void* d_ws, size_t ws_size,
                              hipStream_t stream) {
  const float* x  = (const float*)d_in[0];
  const float* Wg = (const float*)d_in[1];
  const float* bg = (const float*)d_in[2];
  const float* W1 = (const float*)d_in[3];
  const float* b1 = (const float*)d_in[4];
  const float* W2 = (const float*)d_in[5];
  const float* b2 = (const float*)d_in[6];
  float* out = (float*)d_out;

  uint8_t* w = (uint8_t*)d_ws;
  size_t o = 0;
  unsigned short* xb  = (unsigned short*)(w + o); o += (size_t)TT * DD * 2;       // 8 MB
  unsigned short* w1t = (unsigned short*)(w + o); o += (size_t)EE * DD * HH * 2;  // 16 MB
  unsigned short* w2t = (unsigned short*)(w + o); o += (size_t)EE * DD * HH * 2;  // 16 MB
  unsigned short* hb  = (unsigned short*)(w + o); o += (size_t)NSLOT * HH * 2;    // 37.7 MB
  int*   slot_token = (int*)(w + o);   o += (size_t)NSLOT * 4;
  float* slot_w     = (float*)(w + o); o += (size_t)NSLOT * 4;
  int*   slot_of    = (int*)(w + o);   o += (size_t)TT * 2 * 4;
  int*   gate_e     = (int*)(w + o);   o += (size_t)TT * 2 * 4;
  float* gate_w     = (float*)(w + o); o += (size_t)TT * 2 * 4;
  int*   counts     = (int*)(w + o);   o += 64;   // counts[16]
  int*   nretry     = (int*)(w + o);   o += 64;
  int*   fill       = (int*)(w + o);   o += 64;   // one 192B memset covers all 3
  int*   retry      = (int*)(w + o);   o += RETRYCAP * 4;
  unsigned short* yw = (unsigned short*)(w + o);
  size_t need_y = o + (size_t)NSLOT * DD * 2;   // +18.9 MB
  int use_y = (ws_size >= need_y);

  hipMemsetAsync(counts, 0, 192, stream);  // counts + nretry + fill
  if (!use_y) {
    hipMemsetAsync(slot_token, 0xFF, (size_t)NSLOT * 4, stream);
    hipMemsetAsync(d_out, 0, (size_t)TT * DD * 4, stream);
  }

  // gate (blocks 0..127, dispatched first) + W1/W2 transposes (128..4223)
  prep_kernel<<<128 + 4096, 256, 0, stream>>>(
      W1, W2, w1t, w2t, x, Wg, bg, xb, gate_e, gate_w, counts, nretry, retry);
  gatefix_kernel<<<RETRYCAP / 16, 256, 0, stream>>>(x, Wg, bg, nretry, retry,
                                                    gate_e, gate_w, counts);
  scatter_kernel<<<TT / 256, 256, 0, stream>>>(gate_e, gate_w, counts, fill,
                                               slot_token, slot_w, slot_of);
  {
    dim3 g(HH / 256, MAXTILES);
    gemm1_kernel<<<g, 512, 0, stream>>>(xb, w1t, b1, slot_token, counts, hb);
  }
  {
    dim3 g(DD / 256, MAXTILES);
    if (use_y)
      gemm2_kernel<1><<<g, 512, 0, stream>>>(hb, w2t, b2, slot_token, slot_w,
                                             counts, yw, out);
    else
      gemm2_kernel<0><<<g, 512, 0, stream>>>(hb, w2t, b2, slot_token, slot_w,
                                             counts, yw, out);
  }
  if (use_y) {
    combine_kernel<<<TT * (DD / 8) / 256, 256, 0, stream>>>(yw, slot_of, out);
  }
}